// Round 1
// baseline (660.607 us; speedup 1.0000x reference)
//
#include <hip/hip_runtime.h>
#include <hip/hip_bf16.h>

#define T_DIM 1600
#define N_DIM 32
#define C_DIM 512
#define S_DIM 200
#define L_DIM 401
#define NEGF (-1e30f)
#define RCP_LN2 1.44269504088896340736f
#define LN2F 0.69314718055994530942f

static __device__ __forceinline__ float fast_exp2(float x) {
#if __has_builtin(__builtin_amdgcn_exp2f)
    return __builtin_amdgcn_exp2f(x);
#else
    return exp2f(x);
#endif
}

static __device__ __forceinline__ float fast_log2(float x) {
#if __has_builtin(__builtin_amdgcn_logf)
    return __builtin_amdgcn_logf(x);
#else
    return log2f(x);
#endif
}

// logsumexp of two values, base-2 domain. Safe for NEGF sentinels:
//  both NEGF -> NEGF+1 ~ NEGF ; one NEGF -> exp2(-huge)=0 -> returns the other.
static __device__ __forceinline__ float lse2(float a, float b) {
    float m  = fmaxf(a, b);
    float mn = fminf(a, b);
    return m + fast_log2(1.0f + fast_exp2(mn - m));
}

template <int BUF, bool FIRSTCHUNK>
__device__ __forceinline__ void compute_chunk(
    const float (&rows)[2][8][C_DIM], int c8, int lenc, int lane, int tl,
    const int (&labidx)[8], const bool (&allow)[8],
    float &a0, float &a1, float &a2, float &a3,
    float &a4, float &a5, float &a6, float &a7)
{
#pragma unroll
    for (int r = 0; r < 8; ++r) {
        int t = c8 + r;
        if (t >= lenc) break;
        // gather this row's 8 emit values (raw ln-domain log-probs)
        float e0 = rows[BUF][r][labidx[0]];
        float e1 = rows[BUF][r][labidx[1]];
        float e2 = rows[BUF][r][labidx[2]];
        float e3 = rows[BUF][r][labidx[3]];
        float e4 = rows[BUF][r][labidx[4]];
        float e5 = rows[BUF][r][labidx[5]];
        float e6 = rows[BUF][r][labidx[6]];
        float e7 = rows[BUF][r][labidx[7]];
        if (FIRSTCHUNK && r == 0) {
            // t == 0 init: alpha0[0] = emit(blank), alpha0[1] = emit(l1) if tl>=1
            if (lane == 0) {
                a0 = e0 * RCP_LN2;
                a1 = (tl >= 1) ? e1 * RCP_LN2 : NEGF;
            }
        } else {
            // boundary value: state lane*8 - 1 = previous lane's j=7
            float P = __shfl_up(a7, 1);
            P = (lane == 0) ? NEGF : P;
            // even states (blank): q = lse2(self, left); odd states (label):
            // lse2(self, allow ? q_below : left) == lse3 via associativity
            float q0 = lse2(a0, P);
            float n0 = fmaf(e0, RCP_LN2, q0);
            float b1 = allow[1] ? q0 : a0;
            float n1 = fmaf(e1, RCP_LN2, lse2(a1, b1));
            float q2 = lse2(a2, a1);
            float n2 = fmaf(e2, RCP_LN2, q2);
            float b3 = allow[3] ? q2 : a2;
            float n3 = fmaf(e3, RCP_LN2, lse2(a3, b3));
            float q4 = lse2(a4, a3);
            float n4 = fmaf(e4, RCP_LN2, q4);
            float b5 = allow[5] ? q4 : a4;
            float n5 = fmaf(e5, RCP_LN2, lse2(a5, b5));
            float q6 = lse2(a6, a5);
            float n6 = fmaf(e6, RCP_LN2, q6);
            float b7 = allow[7] ? q6 : a6;
            float n7 = fmaf(e7, RCP_LN2, lse2(a7, b7));
            a0 = n0; a1 = n1; a2 = n2; a3 = n3;
            a4 = n4; a5 = n5; a6 = n6; a7 = n7;
        }
    }
}

__global__ __launch_bounds__(64) void ctc_dp(
    const float* __restrict__ lp, const int* __restrict__ tgts,
    const int* __restrict__ input_lens, const int* __restrict__ target_lens,
    float* __restrict__ ws_loss)
{
    __shared__ float rows[2][8][C_DIM];  // 32 KB, double-buffered 8-row chunks
    __shared__ float afin[512];

    const int n = blockIdx.x;
    const int lane = threadIdx.x;
    const int* tgt = tgts + n * S_DIM;

    int len = input_lens[n];
    if (len > T_DIM) len = T_DIM;
    const int lenc = (len < 1) ? 1 : len;
    const int tl = target_lens[n];

    // per-lane extended-label gather indices + skip-allow flags (loop invariant)
    int labidx[8];
    bool allow[8];
#pragma unroll
    for (int j = 0; j < 8; ++j) {
        int s = lane * 8 + j;
        int lab = 0;
        bool al = false;
        if (s & 1) {
            int i = (s - 1) >> 1;
            if (i < S_DIM) {
                lab = tgt[i];
                if (s >= 3 && i >= 1) al = (tgt[i] != tgt[i - 1]);
            }
        }
        if (lab < 0 || lab >= C_DIM) lab = 0;
        labidx[j] = lab;
        allow[j] = al;
    }

    const float4* lp4 = reinterpret_cast<const float4*>(lp);
    float4 stg[8][2];  // one chunk in flight in registers

#define ISSUE_CHUNK(c_) do {                                                  \
        int tb_ = (c_) * 8;                                                   \
        _Pragma("unroll")                                                     \
        for (int r_ = 0; r_ < 8; ++r_) {                                      \
            int t_ = tb_ + r_;                                                \
            if (t_ > lenc - 1) t_ = lenc - 1;                                 \
            size_t b4_ = ((size_t)t_ * N_DIM + n) * (C_DIM / 4);              \
            stg[r_][0] = lp4[b4_ + lane];                                     \
            stg[r_][1] = lp4[b4_ + 64 + lane];                                \
        }                                                                     \
    } while (0)

#define WRITE_CHUNK(B_) do {                                                  \
        _Pragma("unroll")                                                     \
        for (int r_ = 0; r_ < 8; ++r_) {                                      \
            float4* q_ = reinterpret_cast<float4*>(&rows[(B_)][r_][0]);       \
            q_[lane] = stg[r_][0];                                            \
            q_[lane + 64] = stg[r_][1];                                       \
        }                                                                     \
    } while (0)

    float a0 = NEGF, a1 = NEGF, a2 = NEGF, a3 = NEGF;
    float a4 = NEGF, a5 = NEGF, a6 = NEGF, a7 = NEGF;

    // prologue: chunk0 -> buf0, chunk1 staged in regs
    ISSUE_CHUNK(0);
    WRITE_CHUNK(0);
    ISSUE_CHUNK(1);

    const int nc = (lenc + 7) >> 3;        // number of 8-row chunks
    const int ncp = (nc + 1) >> 1;         // chunk pairs

    // peeled first pair (contains the t==0 init)
    compute_chunk<0, true>(rows, 0, lenc, lane, tl, labidx, allow,
                           a0, a1, a2, a3, a4, a5, a6, a7);
    WRITE_CHUNK(1);
    ISSUE_CHUNK(2);
    compute_chunk<1, false>(rows, 8, lenc, lane, tl, labidx, allow,
                            a0, a1, a2, a3, a4, a5, a6, a7);
    WRITE_CHUNK(0);
    ISSUE_CHUNK(3);

    for (int p = 1; p < ncp; ++p) {
        int c8 = p * 16;
        compute_chunk<0, false>(rows, c8, lenc, lane, tl, labidx, allow,
                                a0, a1, a2, a3, a4, a5, a6, a7);
        WRITE_CHUNK(1);
        ISSUE_CHUNK(2 * p + 2);
        compute_chunk<1, false>(rows, c8 + 8, lenc, lane, tl, labidx, allow,
                                a0, a1, a2, a3, a4, a5, a6, a7);
        WRITE_CHUNK(0);
        ISSUE_CHUNK(2 * p + 3);
    }

    // write final alpha to LDS, lane 0 extracts the answer states
    {
        float4 lo = make_float4(a0, a1, a2, a3);
        float4 hi = make_float4(a4, a5, a6, a7);
        reinterpret_cast<float4*>(afin)[lane * 2] = lo;
        reinterpret_cast<float4*>(afin)[lane * 2 + 1] = hi;
    }
    __syncthreads();
    if (lane == 0) {
        int il = 2 * tl;
        if (il < 0) il = 0;
        if (il > L_DIM - 1) il = L_DIM - 1;
        float aL = afin[il];
        float aP = (tl > 0) ? afin[il - 1] : NEGF;
        float m = fmaxf(aL, aP), mn = fminf(aL, aP);
        float l2 = m + fast_log2(1.0f + fast_exp2(mn - m));
        float per_ex = -LN2F * l2;
        if (!(per_ex < 1e29f)) per_ex = 0.0f;  // zero_infinity (also NaN-safe)
        float tlf = (float)tl;
        if (tlf < 1.0f) tlf = 1.0f;
        ws_loss[n] = per_ex / sqrtf(tlf);
    }
#undef ISSUE_CHUNK
#undef WRITE_CHUNK
}

__global__ __launch_bounds__(64) void ctc_reduce(const float* __restrict__ wsf,
                                                 float* __restrict__ out)
{
    int l = threadIdx.x;
    float v = (l < N_DIM) ? wsf[l] : 0.0f;
#pragma unroll
    for (int off = 32; off >= 1; off >>= 1) v += __shfl_down(v, off);
    if (l == 0) out[0] = v * (1.0f / N_DIM);
}

extern "C" void kernel_launch(void* const* d_in, const int* in_sizes, int n_in,
                              void* d_out, int out_size, void* d_ws, size_t ws_size,
                              hipStream_t stream) {
    (void)in_sizes; (void)n_in; (void)out_size; (void)ws_size;
    const float* lp   = (const float*)d_in[0];
    const int* tgts   = (const int*)d_in[1];
    const int* ilens  = (const int*)d_in[2];
    const int* tlens  = (const int*)d_in[3];
    float* wsf = (float*)d_ws;

    ctc_dp<<<N_DIM, 64, 0, stream>>>(lp, tgts, ilens, tlens, wsf);
    ctc_reduce<<<1, 64, 0, stream>>>(wsf, (float*)d_out);
}

// Round 4
// 564.344 us; speedup vs baseline: 1.1706x; 1.1706x over previous
//
#include <hip/hip_runtime.h>
#include <hip/hip_bf16.h>

#define T_DIM 1600
#define N_DIM 32
#define C_DIM 512
#define S_DIM 200
#define L_DIM 401
#define RCP_LN2 1.44269504088896340736f
#define LN2F 0.69314718055994530942f
#define ESENT (-(1 << 28))

static __device__ __forceinline__ float fast_exp2(float x) {
#if __has_builtin(__builtin_amdgcn_exp2f)
    return __builtin_amdgcn_exp2f(x);
#else
    return exp2f(x);
#endif
}

static __device__ __forceinline__ float fast_log2(float x) {
#if __has_builtin(__builtin_amdgcn_logf)
    return __builtin_amdgcn_logf(x);
#else
    return log2f(x);
#endif
}

// Linear-domain CTC step, 8 states/lane, per-lane block-floating-point scale.
// Even states (blank) share p_blank; odd states gather their label prob.
// Cross-lane: P = prev-lane a7 (state lane*8-1), rescaled by scale_d
// (= 2^(E_prev - E), constant within a chunk; 0 for lane 0).
// Overflow-safety invariant (enforced at BOUNDARY): E_prev - E <= 32, so
// scale_d <= 2^32 and all intra-chunk values stay far below 2^127.
template <int BUF, bool FIRSTCHUNK>
__device__ __forceinline__ void compute_chunk(
    const float (&rows)[2][8][C_DIM], int c8, int lenc, int lane, int tl,
    const int (&labidx)[4], const float (&sk)[4], float scale_d,
    float &a0, float &a1, float &a2, float &a3,
    float &a4, float &a5, float &a6, float &a7)
{
#pragma unroll
    for (int r = 0; r < 8; ++r) {
        int t = c8 + r;
        if (t >= lenc) break;
        float lb = rows[BUF][r][0];           // blank: broadcast, conflict-free
        float g1 = rows[BUF][r][labidx[0]];
        float g3 = rows[BUF][r][labidx[1]];
        float g5 = rows[BUF][r][labidx[2]];
        float g7 = rows[BUF][r][labidx[3]];
        float pb = fast_exp2(lb * RCP_LN2);
        float p1 = fast_exp2(g1 * RCP_LN2);
        float p3 = fast_exp2(g3 * RCP_LN2);
        float p5 = fast_exp2(g5 * RCP_LN2);
        float p7 = fast_exp2(g7 * RCP_LN2);
        if (FIRSTCHUNK && r == 0) {
            if (lane == 0) {
                a0 = pb;
                a1 = (tl >= 1) ? p1 : 0.0f;
            }
        } else {
            float P = __shfl_up(a7, 1) * scale_d;   // scale_d==0 on lane 0
            float n0 = (a0 + P) * pb;
            float n1 = fmaf(sk[0], P,  a1 + a0) * p1;
            float n2 = (a2 + a1) * pb;
            float n3 = fmaf(sk[1], a1, a3 + a2) * p3;
            float n4 = (a4 + a3) * pb;
            float n5 = fmaf(sk[2], a3, a5 + a4) * p5;
            float n6 = (a6 + a5) * pb;
            float n7 = fmaf(sk[3], a5, a7 + a6) * p7;
            a0 = n0; a1 = n1; a2 = n2; a3 = n3;
            a4 = n4; a5 = n5; a6 = n6; a7 = n7;
        }
    }
}

__global__ __launch_bounds__(64) void ctc_dp(
    const float* __restrict__ lp, const int* __restrict__ tgts,
    const int* __restrict__ input_lens, const int* __restrict__ target_lens,
    float* __restrict__ ws_loss)
{
    __shared__ float rows[2][8][C_DIM];  // 32 KB double-buffered staging
    __shared__ float afin[512];
    __shared__ int escale[64];

    const int n = blockIdx.x;
    const int lane = threadIdx.x;
    const int* tgt = tgts + n * S_DIM;

    int len = input_lens[n];
    if (len > T_DIM) len = T_DIM;
    const int lenc = (len < 1) ? 1 : len;
    const int tl = target_lens[n];

    // odd-state labels (s = lane*8 + {1,3,5,7}) + skip-allow multipliers
    int labidx[4];
    float sk[4];
#pragma unroll
    for (int jj = 0; jj < 4; ++jj) {
        int s = lane * 8 + 2 * jj + 1;
        int i = (s - 1) >> 1;
        int lab = 0;
        float al = 0.0f;
        if (i < S_DIM) {
            lab = tgt[i];
            if (s >= 3 && i >= 1) al = (tgt[i] != tgt[i - 1]) ? 1.0f : 0.0f;
        }
        if (lab < 0 || lab >= C_DIM) lab = 0;
        labidx[jj] = lab;
        sk[jj] = al;
    }

    const float4* lp4 = reinterpret_cast<const float4*>(lp);
    float4 stg[8][2];

#define ISSUE_CHUNK(c_) do {                                                  \
        int tb_ = (c_) * 8;                                                   \
        _Pragma("unroll")                                                     \
        for (int r_ = 0; r_ < 8; ++r_) {                                      \
            int t_ = tb_ + r_;                                                \
            if (t_ > lenc - 1) t_ = lenc - 1;                                 \
            size_t b4_ = ((size_t)t_ * N_DIM + n) * (C_DIM / 4);              \
            stg[r_][0] = lp4[b4_ + lane];                                     \
            stg[r_][1] = lp4[b4_ + 64 + lane];                                \
        }                                                                     \
    } while (0)

#define WRITE_CHUNK(B_) do {                                                  \
        _Pragma("unroll")                                                     \
        for (int r_ = 0; r_ < 8; ++r_) {                                      \
            float4* q_ = reinterpret_cast<float4*>(&rows[(B_)][r_][0]);       \
            q_[lane] = stg[r_][0];                                            \
            q_[lane + 64] = stg[r_][1];                                       \
        }                                                                     \
    } while (0)

    // Chunk-boundary per-lane renormalization.
    // prop[j] = true log2 of lane max (or ESENT if lane empty).
    // E_fin[j] = max(prop[j], E_fin[j-1] - 32)  -- enforced via prefix-max of
    // G[j] = prop[j] + 32j. Guarantees next-chunk scale_d = 2^(d) with d<=32.
#define BOUNDARY() do {                                                       \
        float lm_ = fmaxf(fmaxf(fmaxf(a0, a1), fmaxf(a2, a3)),                \
                          fmaxf(fmaxf(a4, a5), fmaxf(a6, a7)));               \
        bool nz_ = (lm_ > 0.0f);                                              \
        int kl_ = (int)((__float_as_uint(lm_) >> 23) & 0xffu) - 127;          \
        int prop_ = nz_ ? (E + kl_) : ESENT;                                  \
        int g_ = prop_ + 32 * lane;                                           \
        _Pragma("unroll")                                                     \
        for (int o_ = 1; o_ < 64; o_ <<= 1) {                                 \
            int t_ = __shfl_up(g_, o_);                                       \
            if (lane >= o_) g_ = (t_ > g_) ? t_ : g_;                         \
        }                                                                     \
        int Efin_ = g_ - 32 * lane;                                           \
        if (nz_) {                                                            \
            int sh_ = E - Efin_;          /* <= -kl_ <= 127: no overflow */   \
            int h1_ = sh_ / 2, h2_ = sh_ - h1_;                               \
            float f_ = fast_exp2((float)h1_), gg_ = fast_exp2((float)h2_);    \
            float fg_ = f_ * gg_;                                             \
            a0 *= fg_; a1 *= fg_; a2 *= fg_; a3 *= fg_;                       \
            a4 *= fg_; a5 *= fg_; a6 *= fg_; a7 *= fg_;                       \
        }                                                                     \
        int Eprev_ = __shfl_up(Efin_, 1);                                     \
        E = Efin_;                                                            \
        if (lane == 0) {                                                      \
            scale_d = 0.0f;                                                   \
        } else {                                                              \
            int d_ = Eprev_ - Efin_;      /* d_ <= 32 by construction */      \
            scale_d = (d_ < -126) ? 0.0f : fast_exp2((float)d_);              \
        }                                                                     \
    } while (0)

    float a0 = 0.0f, a1 = 0.0f, a2 = 0.0f, a3 = 0.0f;
    float a4 = 0.0f, a5 = 0.0f, a6 = 0.0f, a7 = 0.0f;
    int E = 0;
    float scale_d = (lane == 0) ? 0.0f : 1.0f;

    ISSUE_CHUNK(0);
    WRITE_CHUNK(0);
    ISSUE_CHUNK(1);

    const int nc = (lenc + 7) >> 3;
    const int ncp = (nc + 1) >> 1;

    compute_chunk<0, true>(rows, 0, lenc, lane, tl, labidx, sk, scale_d,
                           a0, a1, a2, a3, a4, a5, a6, a7);
    BOUNDARY();
    WRITE_CHUNK(1);
    ISSUE_CHUNK(2);
    compute_chunk<1, false>(rows, 8, lenc, lane, tl, labidx, sk, scale_d,
                            a0, a1, a2, a3, a4, a5, a6, a7);
    BOUNDARY();
    WRITE_CHUNK(0);
    ISSUE_CHUNK(3);

    for (int p = 1; p < ncp; ++p) {
        int c8 = p * 16;
        compute_chunk<0, false>(rows, c8, lenc, lane, tl, labidx, sk, scale_d,
                                a0, a1, a2, a3, a4, a5, a6, a7);
        BOUNDARY();
        WRITE_CHUNK(1);
        ISSUE_CHUNK(2 * p + 2);
        compute_chunk<1, false>(rows, c8 + 8, lenc, lane, tl, labidx, sk,
                                scale_d, a0, a1, a2, a3, a4, a5, a6, a7);
        BOUNDARY();
        WRITE_CHUNK(0);
        ISSUE_CHUNK(2 * p + 3);
    }

    {
        float4 lo = make_float4(a0, a1, a2, a3);
        float4 hi = make_float4(a4, a5, a6, a7);
        reinterpret_cast<float4*>(afin)[lane * 2] = lo;
        reinterpret_cast<float4*>(afin)[lane * 2 + 1] = hi;
        escale[lane] = E;
    }
    __syncthreads();
    if (lane == 0) {
        int il = 2 * tl;
        if (il < 0) il = 0;
        if (il > L_DIM - 1) il = L_DIM - 1;
        float aL = afin[il];
        float xL = (aL > 0.0f)
                 ? fast_log2(aL) + (float)escale[il >> 3] : -1e30f;
        float xP = -1e30f;
        if (tl > 0 && il >= 1) {
            float aP = afin[il - 1];
            if (aP > 0.0f) xP = fast_log2(aP) + (float)escale[(il - 1) >> 3];
        }
        float m = fmaxf(xL, xP), mn = fminf(xL, xP);
        float l2 = m + fast_log2(1.0f + fast_exp2(mn - m));  // sentinel-safe
        float per_ex = -LN2F * l2;
        if (!(per_ex < 1e29f)) per_ex = 0.0f;  // zero_infinity (NaN/inf safe)
        float tlf = (float)tl;
        if (tlf < 1.0f) tlf = 1.0f;
        ws_loss[n] = per_ex / sqrtf(tlf);
    }
#undef ISSUE_CHUNK
#undef WRITE_CHUNK
#undef BOUNDARY
}

__global__ __launch_bounds__(64) void ctc_reduce(const float* __restrict__ wsf,
                                                 float* __restrict__ out)
{
    int l = threadIdx.x;
    float v = (l < N_DIM) ? wsf[l] : 0.0f;
#pragma unroll
    for (int off = 32; off >= 1; off >>= 1) v += __shfl_down(v, off);
    if (l == 0) out[0] = v * (1.0f / N_DIM);
}

extern "C" void kernel_launch(void* const* d_in, const int* in_sizes, int n_in,
                              void* d_out, int out_size, void* d_ws, size_t ws_size,
                              hipStream_t stream) {
    (void)in_sizes; (void)n_in; (void)out_size; (void)ws_size;
    const float* lp   = (const float*)d_in[0];
    const int* tgts   = (const int*)d_in[1];
    const int* ilens  = (const int*)d_in[2];
    const int* tlens  = (const int*)d_in[3];
    float* wsf = (float*)d_ws;

    ctc_dp<<<N_DIM, 64, 0, stream>>>(lp, tgts, ilens, tlens, wsf);
    ctc_reduce<<<1, 64, 0, stream>>>(wsf, (float*)d_out);
}

// Round 5
// 492.272 us; speedup vs baseline: 1.3420x; 1.1464x over previous
//
#include <hip/hip_runtime.h>
#include <hip/hip_bf16.h>

#define T_DIM 1600
#define N_DIM 32
#define C_DIM 512
#define S_DIM 200
#define L_DIM 401
#define RCP_LN2 1.44269504088896340736f
#define LN2F 0.69314718055994530942f
#define ESENT (-(1 << 28))

static __device__ __forceinline__ float fast_exp2(float x) {
#if __has_builtin(__builtin_amdgcn_exp2f)
    return __builtin_amdgcn_exp2f(x);
#else
    return exp2f(x);
#endif
}

static __device__ __forceinline__ float fast_log2(float x) {
#if __has_builtin(__builtin_amdgcn_logf)
    return __builtin_amdgcn_logf(x);
#else
    return log2f(x);
#endif
}

// ---- DPP cross-lane helpers (VALU pipe, ~4 cyc, replaces ds_bpermute) ----
// wave_shr:1 = 0x138; row_shr:N = 0x110+N; row_bcast15=0x142; row_bcast31=0x143.
// update_dpp(old, src, ...): lanes with invalid DPP source keep `old`.

static __device__ __forceinline__ float dpp_shr1_f(float x) {
    // lane 0 gets 0.0f (old = 0)
    return __int_as_float(__builtin_amdgcn_update_dpp(
        0, __float_as_int(x), 0x138, 0xf, 0xf, false));
}

static __device__ __forceinline__ int dpp_shr1_i(int x, int old0) {
    return __builtin_amdgcn_update_dpp(old0, x, 0x138, 0xf, 0xf, false);
}

// inclusive prefix-max over 64 lanes; max is idempotent so old=x makes every
// invalid/masked read a no-op (no row_mask gymnastics needed).
static __device__ __forceinline__ int dpp_prefix_max_i(int x) {
    int t;
    t = __builtin_amdgcn_update_dpp(x, x, 0x111, 0xf, 0xf, false); x = (t > x) ? t : x;
    t = __builtin_amdgcn_update_dpp(x, x, 0x112, 0xf, 0xf, false); x = (t > x) ? t : x;
    t = __builtin_amdgcn_update_dpp(x, x, 0x114, 0xf, 0xf, false); x = (t > x) ? t : x;
    t = __builtin_amdgcn_update_dpp(x, x, 0x118, 0xf, 0xf, false); x = (t > x) ? t : x;
    t = __builtin_amdgcn_update_dpp(x, x, 0x142, 0xf, 0xf, false); x = (t > x) ? t : x;
    t = __builtin_amdgcn_update_dpp(x, x, 0x143, 0xf, 0xf, false); x = (t > x) ? t : x;
    return x;
}

__global__ __launch_bounds__(64) void ctc_dp(
    const float* __restrict__ lp, const int* __restrict__ tgts,
    const int* __restrict__ input_lens, const int* __restrict__ target_lens,
    float* __restrict__ ws_loss)
{
    __shared__ float rows[2][8][C_DIM];  // 32 KB double-buffered staging
    __shared__ float afin[512];
    __shared__ int escale[64];

    const int n = blockIdx.x;
    const int lane = threadIdx.x;
    const int* tgt = tgts + n * S_DIM;

    int len = input_lens[n];
    if (len > T_DIM) len = T_DIM;
    const int lenc = (len < 1) ? 1 : len;
    const int tl = target_lens[n];

    // odd-state labels (s = lane*8 + {1,3,5,7}) + skip-allow multipliers
    int labidx[4];
    float sk[4];
#pragma unroll
    for (int jj = 0; jj < 4; ++jj) {
        int s = lane * 8 + 2 * jj + 1;
        int i = (s - 1) >> 1;
        int lab = 0;
        float al = 0.0f;
        if (i < S_DIM) {
            lab = tgt[i];
            if (s >= 3 && i >= 1) al = (tgt[i] != tgt[i - 1]) ? 1.0f : 0.0f;
        }
        if (lab < 0 || lab >= C_DIM) lab = 0;
        labidx[jj] = lab;
        sk[jj] = al;
    }

    const float4* lp4 = reinterpret_cast<const float4*>(lp);
    float4 stg[8][2];

#define ISSUE_CHUNK(c_) do {                                                  \
        int tb_ = (c_) * 8;                                                   \
        _Pragma("unroll")                                                     \
        for (int r_ = 0; r_ < 8; ++r_) {                                      \
            int t_ = tb_ + r_;                                                \
            if (t_ > lenc - 1) t_ = lenc - 1;                                 \
            size_t b4_ = ((size_t)t_ * N_DIM + n) * (C_DIM / 4);              \
            stg[r_][0] = lp4[b4_ + lane];                                     \
            stg[r_][1] = lp4[b4_ + 64 + lane];                                \
        }                                                                     \
    } while (0)

#define WRITE_CHUNK(B_) do {                                                  \
        _Pragma("unroll")                                                     \
        for (int r_ = 0; r_ < 8; ++r_) {                                      \
            float4* q_ = reinterpret_cast<float4*>(&rows[(B_)][r_][0]);       \
            q_[lane] = stg[r_][0];                                            \
            q_[lane + 64] = stg[r_][1];                                       \
        }                                                                     \
    } while (0)

    // Gather chunk emits into registers (issued a full chunk before use; DS
    // pipe is in-order so these observe the preceding WRITE_CHUNK).
#define GATHER(B_, gb_, q1_, q3_, q5_, q7_) do {                              \
        _Pragma("unroll")                                                     \
        for (int r_ = 0; r_ < 8; ++r_) {                                      \
            gb_[r_] = rows[(B_)][r_][0];                                      \
            q1_[r_] = rows[(B_)][r_][labidx[0]];                              \
            q3_[r_] = rows[(B_)][r_][labidx[1]];                              \
            q5_[r_] = rows[(B_)][r_][labidx[2]];                              \
            q7_[r_] = rows[(B_)][r_][labidx[3]];                              \
        }                                                                     \
    } while (0)

    // 8 linear-domain DP steps from registers. Cross-lane P via DPP wave_shr1.
#define COMPUTE(c8_, FIRST_, gb_, q1_, q3_, q5_, q7_) do {                    \
        _Pragma("unroll")                                                     \
        for (int r_ = 0; r_ < 8; ++r_) {                                      \
            int t_ = (c8_) + r_;                                              \
            if (t_ >= lenc) break;                                            \
            float pb_ = fast_exp2(gb_[r_] * RCP_LN2);                         \
            float p1_ = fast_exp2(q1_[r_] * RCP_LN2);                         \
            float p3_ = fast_exp2(q3_[r_] * RCP_LN2);                         \
            float p5_ = fast_exp2(q5_[r_] * RCP_LN2);                         \
            float p7_ = fast_exp2(q7_[r_] * RCP_LN2);                         \
            if ((FIRST_) && r_ == 0) {                                        \
                if (lane == 0) {                                              \
                    a0 = pb_;                                                 \
                    a1 = (tl >= 1) ? p1_ : 0.0f;                              \
                }                                                             \
            } else {                                                          \
                float P_ = dpp_shr1_f(a7) * scale_d;                          \
                float n0_ = (a0 + P_) * pb_;                                  \
                float n1_ = fmaf(sk[0], P_,  a1 + a0) * p1_;                  \
                float n2_ = (a2 + a1) * pb_;                                  \
                float n3_ = fmaf(sk[1], a1, a3 + a2) * p3_;                   \
                float n4_ = (a4 + a3) * pb_;                                  \
                float n5_ = fmaf(sk[2], a3, a5 + a4) * p5_;                   \
                float n6_ = (a6 + a5) * pb_;                                  \
                float n7_ = fmaf(sk[3], a5, a7 + a6) * p7_;                   \
                a0 = n0_; a1 = n1_; a2 = n2_; a3 = n3_;                       \
                a4 = n4_; a5 = n5_; a6 = n6_; a7 = n7_;                       \
            }                                                                 \
        }                                                                     \
    } while (0)

    // Chunk-boundary per-lane renormalization. E_fin[j] = max(prop[j],
    // E_fin[j-1]-32) via DPP prefix-max of G = prop + 32*lane. Guarantees
    // next-chunk scale_d = 2^d with d <= 32 (no overflow possible).
#define BOUNDARY() do {                                                       \
        float lm_ = fmaxf(fmaxf(fmaxf(a0, a1), fmaxf(a2, a3)),                \
                          fmaxf(fmaxf(a4, a5), fmaxf(a6, a7)));               \
        bool nz_ = (lm_ > 0.0f);                                              \
        int kl_ = (int)((__float_as_uint(lm_) >> 23) & 0xffu) - 127;          \
        int prop_ = nz_ ? (E + kl_) : ESENT;                                  \
        int g_ = dpp_prefix_max_i(prop_ + 32 * lane);                         \
        int Efin_ = g_ - 32 * lane;                                           \
        if (nz_) {                                                            \
            int sh_ = E - Efin_;                                              \
            int h1_ = sh_ / 2, h2_ = sh_ - h1_;                               \
            float f_ = fast_exp2((float)h1_), gg_ = fast_exp2((float)h2_);    \
            float fg_ = f_ * gg_;                                             \
            a0 *= fg_; a1 *= fg_; a2 *= fg_; a3 *= fg_;                       \
            a4 *= fg_; a5 *= fg_; a6 *= fg_; a7 *= fg_;                       \
        }                                                                     \
        int Eprev_ = dpp_shr1_i(Efin_, ESENT);                                \
        E = Efin_;                                                            \
        if (lane == 0) {                                                      \
            scale_d = 0.0f;                                                   \
        } else {                                                              \
            int d_ = Eprev_ - Efin_;      /* d_ <= 32 by construction */      \
            scale_d = (d_ < -126) ? 0.0f : fast_exp2((float)d_);              \
        }                                                                     \
    } while (0)

    float a0 = 0.0f, a1 = 0.0f, a2 = 0.0f, a3 = 0.0f;
    float a4 = 0.0f, a5 = 0.0f, a6 = 0.0f, a7 = 0.0f;
    int E = 0;
    float scale_d = (lane == 0) ? 0.0f : 1.0f;

    float gbA[8], q1A[8], q3A[8], q5A[8], q7A[8];
    float gbB[8], q1B[8], q3B[8], q5B[8], q7B[8];

    // prologue: chunk0 staged+gathered, chunk1 loads in flight
    ISSUE_CHUNK(0);
    WRITE_CHUNK(0);
    ISSUE_CHUNK(1);
    GATHER(0, gbA, q1A, q3A, q5A, q7A);

    const int nc = (lenc + 7) >> 3;
    const int ncp = (nc + 1) >> 1;

    // peeled pair 0 (contains t==0 init)
    WRITE_CHUNK(1);
    ISSUE_CHUNK(2);
    GATHER(1, gbB, q1B, q3B, q5B, q7B);
    COMPUTE(0, true, gbA, q1A, q3A, q5A, q7A);
    BOUNDARY();
    WRITE_CHUNK(0);
    ISSUE_CHUNK(3);
    GATHER(0, gbA, q1A, q3A, q5A, q7A);
    COMPUTE(8, false, gbB, q1B, q3B, q5B, q7B);
    BOUNDARY();

    for (int p = 1; p < ncp; ++p) {
        int c8 = p * 16;
        WRITE_CHUNK(1);
        ISSUE_CHUNK(2 * p + 2);
        GATHER(1, gbB, q1B, q3B, q5B, q7B);
        COMPUTE(c8, false, gbA, q1A, q3A, q5A, q7A);
        BOUNDARY();
        WRITE_CHUNK(0);
        ISSUE_CHUNK(2 * p + 3);
        GATHER(0, gbA, q1A, q3A, q5A, q7A);
        COMPUTE(c8 + 8, false, gbB, q1B, q3B, q5B, q7B);
        BOUNDARY();
    }

    {
        float4 lo = make_float4(a0, a1, a2, a3);
        float4 hi = make_float4(a4, a5, a6, a7);
        reinterpret_cast<float4*>(afin)[lane * 2] = lo;
        reinterpret_cast<float4*>(afin)[lane * 2 + 1] = hi;
        escale[lane] = E;
    }
    __syncthreads();
    if (lane == 0) {
        int il = 2 * tl;
        if (il < 0) il = 0;
        if (il > L_DIM - 1) il = L_DIM - 1;
        float aL = afin[il];
        float xL = (aL > 0.0f)
                 ? fast_log2(aL) + (float)escale[il >> 3] : -1e30f;
        float xP = -1e30f;
        if (tl > 0 && il >= 1) {
            float aP = afin[il - 1];
            if (aP > 0.0f) xP = fast_log2(aP) + (float)escale[(il - 1) >> 3];
        }
        float m = fmaxf(xL, xP), mn = fminf(xL, xP);
        float l2 = m + fast_log2(1.0f + fast_exp2(mn - m));  // sentinel-safe
        float per_ex = -LN2F * l2;
        if (!(per_ex < 1e29f)) per_ex = 0.0f;  // zero_infinity (NaN/inf safe)
        float tlf = (float)tl;
        if (tlf < 1.0f) tlf = 1.0f;
        ws_loss[n] = per_ex / sqrtf(tlf);
    }
#undef ISSUE_CHUNK
#undef WRITE_CHUNK
#undef GATHER
#undef COMPUTE
#undef BOUNDARY
}

__global__ __launch_bounds__(64) void ctc_reduce(const float* __restrict__ wsf,
                                                 float* __restrict__ out)
{
    int l = threadIdx.x;
    float v = (l < N_DIM) ? wsf[l] : 0.0f;
#pragma unroll
    for (int off = 32; off >= 1; off >>= 1) v += __shfl_down(v, off);
    if (l == 0) out[0] = v * (1.0f / N_DIM);
}

extern "C" void kernel_launch(void* const* d_in, const int* in_sizes, int n_in,
                              void* d_out, int out_size, void* d_ws, size_t ws_size,
                              hipStream_t stream) {
    (void)in_sizes; (void)n_in; (void)out_size; (void)ws_size;
    const float* lp   = (const float*)d_in[0];
    const int* tgts   = (const int*)d_in[1];
    const int* ilens  = (const int*)d_in[2];
    const int* tlens  = (const int*)d_in[3];
    float* wsf = (float*)d_ws;

    ctc_dp<<<N_DIM, 64, 0, stream>>>(lp, tgts, ilens, tlens, wsf);
    ctc_reduce<<<1, 64, 0, stream>>>(wsf, (float*)d_out);
}

// Round 6
// 444.757 us; speedup vs baseline: 1.4853x; 1.1068x over previous
//
#include <hip/hip_runtime.h>
#include <hip/hip_bf16.h>

#define T_DIM 1600
#define N_DIM 32
#define C_DIM 512
#define S_DIM 200
#define L_DIM 401
#define RCP_LN2 1.44269504088896340736f
#define LN2F 0.69314718055994530942f
#define ESENT (-(1 << 28))

static __device__ __forceinline__ float fast_exp2(float x) {
#if __has_builtin(__builtin_amdgcn_exp2f)
    return __builtin_amdgcn_exp2f(x);
#else
    return exp2f(x);
#endif
}

static __device__ __forceinline__ float fast_log2(float x) {
#if __has_builtin(__builtin_amdgcn_logf)
    return __builtin_amdgcn_logf(x);
#else
    return log2f(x);
#endif
}

// ---- DPP cross-lane helpers (VALU pipe, replaces ds_bpermute) ----
static __device__ __forceinline__ float dpp_shr1_f(float x) {
    return __int_as_float(__builtin_amdgcn_update_dpp(
        0, __float_as_int(x), 0x138, 0xf, 0xf, false));  // lane0 -> 0.0f
}
static __device__ __forceinline__ int dpp_shr1_i(int x, int old0) {
    return __builtin_amdgcn_update_dpp(old0, x, 0x138, 0xf, 0xf, false);
}
static __device__ __forceinline__ int dpp_prefix_max_i(int x) {
    int t;
    t = __builtin_amdgcn_update_dpp(x, x, 0x111, 0xf, 0xf, false); x = (t > x) ? t : x;
    t = __builtin_amdgcn_update_dpp(x, x, 0x112, 0xf, 0xf, false); x = (t > x) ? t : x;
    t = __builtin_amdgcn_update_dpp(x, x, 0x114, 0xf, 0xf, false); x = (t > x) ? t : x;
    t = __builtin_amdgcn_update_dpp(x, x, 0x118, 0xf, 0xf, false); x = (t > x) ? t : x;
    t = __builtin_amdgcn_update_dpp(x, x, 0x142, 0xf, 0xf, false); x = (t > x) ? t : x;
    t = __builtin_amdgcn_update_dpp(x, x, 0x143, 0xf, 0xf, false); x = (t > x) ? t : x;
    return x;
}

// async HBM -> LDS, 16 B/lane; lds base must be wave-uniform (HW adds lane*16)
static __device__ __forceinline__ void gl_lds16(const float* g, float* l) {
    __builtin_amdgcn_global_load_lds(
        (const __attribute__((address_space(1))) unsigned int*)g,
        (__attribute__((address_space(3))) unsigned int*)l, 16, 0, 0);
}

// s_waitcnt immediates (gfx9 encoding): vmcnt lo [3:0], expcnt [6:4],
// lgkmcnt [11:8], vmcnt hi [15:14]
#define VMWAIT16() __builtin_amdgcn_s_waitcnt(0x4F70)  // vmcnt(16)
#define VMWAIT0()  __builtin_amdgcn_s_waitcnt(0x0F70)  // vmcnt(0)

__global__ __launch_bounds__(64) void ctc_dp(
    const float* __restrict__ lp, const int* __restrict__ tgts,
    const int* __restrict__ input_lens, const int* __restrict__ target_lens,
    float* __restrict__ ws_loss)
{
    __shared__ float rows[3][8][C_DIM];  // 48 KB triple-buffered staging
    __shared__ float afin[512];
    __shared__ int escale[64];

    const int n = blockIdx.x;
    const int lane = threadIdx.x;
    const int* tgt = tgts + n * S_DIM;

    int len = input_lens[n];
    if (len > T_DIM) len = T_DIM;
    const int lenc = (len < 1) ? 1 : len;
    const int tl = target_lens[n];

    int labidx[4];
    float sk[4];
#pragma unroll
    for (int jj = 0; jj < 4; ++jj) {
        int s = lane * 8 + 2 * jj + 1;
        int i = (s - 1) >> 1;
        int lab = 0;
        float al = 0.0f;
        if (i < S_DIM) {
            lab = tgt[i];
            if (s >= 3 && i >= 1) al = (tgt[i] != tgt[i - 1]) ? 1.0f : 0.0f;
        }
        if (lab < 0 || lab >= C_DIM) lab = 0;
        labidx[jj] = lab;
        sk[jj] = al;
    }

    // 16 async load instructions per chunk (8 rows x 2 halves), always 16
    // so vmcnt bookkeeping stays invariant (tail chunks clamp t).
#define ISSUE(c_, B_) do {                                                    \
        int tb_ = (c_) * 8;                                                   \
        _Pragma("unroll")                                                     \
        for (int r_ = 0; r_ < 8; ++r_) {                                      \
            int t_ = tb_ + r_;                                                \
            if (t_ > lenc - 1) t_ = lenc - 1;                                 \
            const float* g_ = lp + ((size_t)t_ * N_DIM + n) * C_DIM + lane*4; \
            gl_lds16(g_,        &rows[(B_)][r_][0]);                          \
            gl_lds16(g_ + 256,  &rows[(B_)][r_][256]);                        \
        }                                                                     \
    } while (0)

#define GATHER(B_, gb_, q1_, q3_, q5_, q7_) do {                              \
        _Pragma("unroll")                                                     \
        for (int r_ = 0; r_ < 8; ++r_) {                                      \
            gb_[r_] = rows[(B_)][r_][0];                                      \
            q1_[r_] = rows[(B_)][r_][labidx[0]];                              \
            q3_[r_] = rows[(B_)][r_][labidx[1]];                              \
            q5_[r_] = rows[(B_)][r_][labidx[2]];                              \
            q7_[r_] = rows[(B_)][r_][labidx[3]];                              \
        }                                                                     \
    } while (0)

#define COMPUTE(c8_, FIRST_, gb_, q1_, q3_, q5_, q7_) do {                    \
        _Pragma("unroll")                                                     \
        for (int r_ = 0; r_ < 8; ++r_) {                                      \
            int t_ = (c8_) + r_;                                              \
            if (t_ >= lenc) break;                                            \
            float pb_ = fast_exp2(gb_[r_] * RCP_LN2);                         \
            float p1_ = fast_exp2(q1_[r_] * RCP_LN2);                         \
            float p3_ = fast_exp2(q3_[r_] * RCP_LN2);                         \
            float p5_ = fast_exp2(q5_[r_] * RCP_LN2);                         \
            float p7_ = fast_ex2_guard(0); /* placeholder removed below */    \
        }                                                                     \
    } while (0)
#undef COMPUTE
#define COMPUTE(c8_, FIRST_, gb_, q1_, q3_, q5_, q7_) do {                    \
        _Pragma("unroll")                                                     \
        for (int r_ = 0; r_ < 8; ++r_) {                                      \
            int t_ = (c8_) + r_;                                              \
            if (t_ >= lenc) break;                                            \
            float pb_ = fast_exp2(gb_[r_] * RCP_LN2);                         \
            float p1_ = fast_exp2(q1_[r_] * RCP_LN2);                         \
            float p3_ = fast_exp2(q3_[r_] * RCP_LN2);                         \
            float p5_ = fast_exp2(q5_[r_] * RCP_LN2);                         \
            float p7_ = fast_exp2(q7_[r_] * RCP_LN2);                         \
            if ((FIRST_) && r_ == 0) {                                        \
                if (lane == 0) {                                              \
                    a0 = pb_;                                                 \
                    a1 = (tl >= 1) ? p1_ : 0.0f;                              \
                }                                                             \
            } else {                                                          \
                float P_ = dpp_shr1_f(a7) * scale_d;                          \
                float n0_ = (a0 + P_) * pb_;                                  \
                float n1_ = fmaf(sk[0], P_,  a1 + a0) * p1_;                  \
                float n2_ = (a2 + a1) * pb_;                                  \
                float n3_ = fmaf(sk[1], a1, a3 + a2) * p3_;                   \
                float n4_ = (a4 + a3) * pb_;                                  \
                float n5_ = fmaf(sk[2], a3, a5 + a4) * p5_;                   \
                float n6_ = (a6 + a5) * pb_;                                  \
                float n7_ = fmaf(sk[3], a5, a7 + a6) * p7_;                   \
                a0 = n0_; a1 = n1_; a2 = n2_; a3 = n3_;                       \
                a4 = n4_; a5 = n5_; a6 = n6_; a7 = n7_;                       \
            }                                                                 \
        }                                                                     \
    } while (0)

#define BOUNDARY() do {                                                       \
        float lm_ = fmaxf(fmaxf(fmaxf(a0, a1), fmaxf(a2, a3)),                \
                          fmaxf(fmaxf(a4, a5), fmaxf(a6, a7)));               \
        bool nz_ = (lm_ > 0.0f);                                              \
        int kl_ = (int)((__float_as_uint(lm_) >> 23) & 0xffu) - 127;          \
        int prop_ = nz_ ? (E + kl_) : ESENT;                                  \
        int g_ = dpp_prefix_max_i(prop_ + 32 * lane);                         \
        int Efin_ = g_ - 32 * lane;                                           \
        if (nz_) {                                                            \
            int sh_ = E - Efin_;                                              \
            int h1_ = sh_ / 2, h2_ = sh_ - h1_;                               \
            float f_ = fast_exp2((float)h1_), gg_ = fast_exp2((float)h2_);    \
            float fg_ = f_ * gg_;                                             \
            a0 *= fg_; a1 *= fg_; a2 *= fg_; a3 *= fg_;                       \
            a4 *= fg_; a5 *= fg_; a6 *= fg_; a7 *= fg_;                       \
        }                                                                     \
        int Eprev_ = dpp_shr1_i(Efin_, ESENT);                                \
        E = Efin_;                                                            \
        if (lane == 0) {                                                      \
            scale_d = 0.0f;                                                   \
        } else {                                                              \
            int d_ = Eprev_ - Efin_;      /* <= 32 by construction */         \
            scale_d = (d_ < -126) ? 0.0f : fast_exp2((float)d_);              \
        }                                                                     \
    } while (0)

    // phase k: vmwait(16) [drains chunk k+1, issued 2 phases ago];
    // GATHER(k+1); COMPUTE(k); BOUNDARY; ISSUE(k+3 -> buf[k%3]).
    // buf[k%3] is safe to overwrite: its gathered regs were consumed by
    // COMPUTE(k) just above (data dependency drained the ds_reads).
#define PHASE(k_, GB_, GS_, CS_, IB_, F_) do {                                \
        VMWAIT16();                                                           \
        GATHER(GB_, gb##GS_, q1##GS_, q3##GS_, q5##GS_, q7##GS_);             \
        COMPUTE((k_) * 8, F_, gb##CS_, q1##CS_, q3##CS_, q5##CS_, q7##CS_);   \
        BOUNDARY();                                                           \
        ISSUE((k_) + 3, IB_);                                                 \
    } while (0)

    float a0 = 0.0f, a1 = 0.0f, a2 = 0.0f, a3 = 0.0f;
    float a4 = 0.0f, a5 = 0.0f, a6 = 0.0f, a7 = 0.0f;
    int E = 0;
    float scale_d = (lane == 0) ? 0.0f : 1.0f;

    float gbA[8], q1A[8], q3A[8], q5A[8], q7A[8];
    float gbB[8], q1B[8], q3B[8], q5B[8], q7B[8];

    // prologue: chunks 0,1 in flight; drain 0; gather 0; chunk 2 in flight
    ISSUE(0, 0);
    ISSUE(1, 1);
    VMWAIT16();
    GATHER(0, gbA, q1A, q3A, q5A, q7A);
    ISSUE(2, 2);

    const int nc = (lenc + 7) >> 3;
    const int kmax = ((nc + 5) / 6) * 6;

    for (int k6 = 0; k6 < kmax; k6 += 6) {
        bool f0 = (k6 == 0);
        PHASE(k6 + 0, 1, B, A, 0, f0);
        PHASE(k6 + 1, 2, A, B, 1, false);
        PHASE(k6 + 2, 0, B, A, 2, false);
        PHASE(k6 + 3, 1, A, B, 0, false);
        PHASE(k6 + 4, 2, B, A, 1, false);
        PHASE(k6 + 5, 0, A, B, 2, false);
    }

    {
        float4 lo = make_float4(a0, a1, a2, a3);
        float4 hi = make_float4(a4, a5, a6, a7);
        reinterpret_cast<float4*>(afin)[lane * 2] = lo;
        reinterpret_cast<float4*>(afin)[lane * 2 + 1] = hi;
        escale[lane] = E;
    }
    __syncthreads();
    if (lane == 0) {
        int il = 2 * tl;
        if (il < 0) il = 0;
        if (il > L_DIM - 1) il = L_DIM - 1;
        float aL = afin[il];
        float xL = (aL > 0.0f)
                 ? fast_log2(aL) + (float)escale[il >> 3] : -1e30f;
        float xP = -1e30f;
        if (tl > 0 && il >= 1) {
            float aP = afin[il - 1];
            if (aP > 0.0f) xP = fast_log2(aP) + (float)escale[(il - 1) >> 3];
        }
        float m = fmaxf(xL, xP), mn = fminf(xL, xP);
        float l2 = m + fast_log2(1.0f + fast_exp2(mn - m));
        float per_ex = -LN2F * l2;
        if (!(per_ex < 1e29f)) per_ex = 0.0f;  // zero_infinity (NaN/inf safe)
        float tlf = (float)tl;
        if (tlf < 1.0f) tlf = 1.0f;
        ws_loss[n] = per_ex / sqrtf(tlf);
    }
#undef ISSUE
#undef GATHER
#undef COMPUTE
#undef BOUNDARY
#undef PHASE
}

__global__ __launch_bounds__(64) void ctc_reduce(const float* __restrict__ wsf,
                                                 float* __restrict__ out)
{
    int l = threadIdx.x;
    float v = (l < N_DIM) ? wsf[l] : 0.0f;
#pragma unroll
    for (int off = 32; off >= 1; off >>= 1) v += __shfl_down(v, off);
    if (l == 0) out[0] = v * (1.0f / N_DIM);
}

extern "C" void kernel_launch(void* const* d_in, const int* in_sizes, int n_in,
                              void* d_out, int out_size, void* d_ws, size_t ws_size,
                              hipStream_t stream) {
    (void)in_sizes; (void)n_in; (void)out_size; (void)ws_size;
    const float* lp   = (const float*)d_in[0];
    const int* tgts   = (const int*)d_in[1];
    const int* ilens  = (const int*)d_in[2];
    const int* tlens  = (const int*)d_in[3];
    float* wsf = (float*)d_ws;

    ctc_dp<<<N_DIM, 64, 0, stream>>>(lp, tgts, ilens, tlens, wsf);
    ctc_reduce<<<1, 64, 0, stream>>>(wsf, (float*)d_out);
}

// Round 7
// 294.407 us; speedup vs baseline: 2.2439x; 1.5107x over previous
//
#include <hip/hip_runtime.h>
#include <hip/hip_bf16.h>

#define T_DIM 1600
#define N_DIM 32
#define C_DIM 512
#define S_DIM 200
#define L_DIM 401
#define RCP_LN2 1.44269504088896340736f
#define LN2F 0.69314718055994530942f
#define ESENT (-(1 << 28))

static __device__ __forceinline__ float fast_exp2(float x) {
#if __has_builtin(__builtin_amdgcn_exp2f)
    return __builtin_amdgcn_exp2f(x);
#else
    return exp2f(x);
#endif
}

static __device__ __forceinline__ float fast_log2(float x) {
#if __has_builtin(__builtin_amdgcn_logf)
    return __builtin_amdgcn_logf(x);
#else
    return log2f(x);
#endif
}

// ---- DPP cross-lane helpers (VALU pipe) ----
static __device__ __forceinline__ float dpp_shr1_f(float x) {
    return __int_as_float(__builtin_amdgcn_update_dpp(
        0, __float_as_int(x), 0x138, 0xf, 0xf, false));  // lane0 -> 0.0f
}
static __device__ __forceinline__ int dpp_shr1_i(int x, int old0) {
    return __builtin_amdgcn_update_dpp(old0, x, 0x138, 0xf, 0xf, false);
}
static __device__ __forceinline__ int dpp_prefix_max_i(int x) {
    int t;
    t = __builtin_amdgcn_update_dpp(x, x, 0x111, 0xf, 0xf, false); x = (t > x) ? t : x;
    t = __builtin_amdgcn_update_dpp(x, x, 0x112, 0xf, 0xf, false); x = (t > x) ? t : x;
    t = __builtin_amdgcn_update_dpp(x, x, 0x114, 0xf, 0xf, false); x = (t > x) ? t : x;
    t = __builtin_amdgcn_update_dpp(x, x, 0x118, 0xf, 0xf, false); x = (t > x) ? t : x;
    t = __builtin_amdgcn_update_dpp(x, x, 0x142, 0xf, 0xf, false); x = (t > x) ? t : x;
    t = __builtin_amdgcn_update_dpp(x, x, 0x143, 0xf, 0xf, false); x = (t > x) ? t : x;
    return x;
}

// async HBM -> LDS, 16 B/lane; lds base wave-uniform (HW adds lane*16)
static __device__ __forceinline__ void gl_lds16(const float* g, float* l) {
    __builtin_amdgcn_global_load_lds(
        (const __attribute__((address_space(1))) unsigned int*)g,
        (__attribute__((address_space(3))) unsigned int*)l, 16, 0, 0);
}

#define VMWAIT16() __builtin_amdgcn_s_waitcnt(0x4F70)  // vmcnt(16)

__global__ __launch_bounds__(128) void ctc_dp(
    const float* __restrict__ lp, const int* __restrict__ tgts,
    const int* __restrict__ input_lens, const int* __restrict__ target_lens,
    float* __restrict__ ws_loss)
{
    __shared__ float rowsF[3][8][C_DIM];   // 48 KB fwd staging
    __shared__ float rowsB[3][8][C_DIM];   // 48 KB bwd staging
    __shared__ float afin[512];
    __shared__ float bfin[512];            // hat-indexed beta
    __shared__ int escF[64];
    __shared__ int escB[64];

    const int n = blockIdx.x;
    const int tid = threadIdx.x;
    const int wid = tid >> 6;
    const int lane = tid & 63;
    const int* tgt = tgts + n * S_DIM;

    int len = input_lens[n];
    if (len > T_DIM) len = T_DIM;
    const int lenc = (len < 1) ? 1 : len;
    const int tl = target_lens[n];
    const int mid = (lenc + 1) >> 1;   // forward steps t=0..mid-1
    const int nsb = lenc - mid;        // backward steps t=lenc-1..mid

#define TMAP_F(ti_) ((ti_) > mid - 1 ? mid - 1 : (ti_))
#define TMAP_B(ti_) (lenc - 1 - (ti_) < 0 ? 0 : lenc - 1 - (ti_))

#define ISSUE(RW_, B_, c_, TMAP_) do {                                        \
        int tb_ = (c_) * 8;                                                   \
        _Pragma("unroll")                                                     \
        for (int r_ = 0; r_ < 8; ++r_) {                                      \
            int ti_ = tb_ + r_;                                               \
            int t_ = TMAP_(ti_);                                              \
            const float* g_ = lp + ((size_t)t_ * N_DIM + n) * C_DIM + lane*4; \
            gl_lds16(g_,       &RW_[(B_)][r_][0]);                            \
            gl_lds16(g_ + 256, &RW_[(B_)][r_][256]);                          \
        }                                                                     \
    } while (0)

#define GATHER(RW_, B_, LAB_, gb_, q1_, q3_, q5_, q7_) do {                   \
        _Pragma("unroll")                                                     \
        for (int r_ = 0; r_ < 8; ++r_) {                                      \
            gb_[r_] = RW_[(B_)][r_][0];                                       \
            q1_[r_] = RW_[(B_)][r_][LAB_[0]];                                 \
            q3_[r_] = RW_[(B_)][r_][LAB_[1]];                                 \
            q5_[r_] = RW_[(B_)][r_][LAB_[2]];                                 \
            q7_[r_] = RW_[(B_)][r_][LAB_[3]];                                 \
        }                                                                     \
    } while (0)

#define BOUNDARY() do {                                                       \
        float lm_ = fmaxf(fmaxf(fmaxf(a0, a1), fmaxf(a2, a3)),                \
                          fmaxf(fmaxf(a4, a5), fmaxf(a6, a7)));               \
        bool nz_ = (lm_ > 0.0f);                                              \
        int kl_ = (int)((__float_as_uint(lm_) >> 23) & 0xffu) - 127;          \
        int prop_ = nz_ ? (E + kl_) : ESENT;                                  \
        int g_ = dpp_prefix_max_i(prop_ + 32 * lane);                         \
        int Efin_ = g_ - 32 * lane;                                           \
        if (nz_) {                                                            \
            int sh_ = E - Efin_;                                              \
            int h1_ = sh_ / 2, h2_ = sh_ - h1_;                               \
            float f_ = fast_exp2((float)h1_), gg_ = fast_exp2((float)h2_);    \
            float fg_ = f_ * gg_;                                             \
            a0 *= fg_; a1 *= fg_; a2 *= fg_; a3 *= fg_;                       \
            a4 *= fg_; a5 *= fg_; a6 *= fg_; a7 *= fg_;                       \
        }                                                                     \
        int Eprev_ = dpp_shr1_i(Efin_, ESENT);                                \
        E = Efin_;                                                            \
        if (lane == 0) {                                                      \
            scale_d = 0.0f;                                                   \
        } else {                                                              \
            int d_ = Eprev_ - Efin_;      /* <= 32 by construction */         \
            scale_d = (d_ < -126) ? 0.0f : fast_exp2((float)d_);              \
        }                                                                     \
    } while (0)

#define COMPUTE_F(c8_, FIRST_, gb_, q1_, q3_, q5_, q7_) do {                  \
        _Pragma("unroll")                                                     \
        for (int r_ = 0; r_ < 8; ++r_) {                                      \
            int t_ = (c8_) + r_;                                              \
            if (t_ >= mid) break;                                             \
            float pb_ = fast_exp2(gb_[r_] * RCP_LN2);                         \
            float p1_ = fast_exp2(q1_[r_] * RCP_LN2);                         \
            float p3_ = fast_exp2(q3_[r_] * RCP_LN2);                         \
            float p5_ = fast_exp2(q5_[r_] * RCP_LN2);                         \
            float p7_ = fast_exp2(q7_[r_] * RCP_LN2);                         \
            if ((FIRST_) && r_ == 0) {                                        \
                if (lane == 0) {                                              \
                    a0 = pb_;                                                 \
                    a1 = (tl >= 1) ? p1_ : 0.0f;                              \
                }                                                             \
            } else {                                                          \
                float P_ = dpp_shr1_f(a7) * scale_d;                          \
                float n0_ = (a0 + P_) * pb_;                                  \
                float n1_ = fmaf(sk[0], P_,  a1 + a0) * p1_;                  \
                float n2_ = (a2 + a1) * pb_;                                  \
                float n3_ = fmaf(sk[1], a1, a3 + a2) * p3_;                   \
                float n4_ = (a4 + a3) * pb_;                                  \
                float n5_ = fmaf(sk[2], a3, a5 + a4) * p5_;                   \
                float n6_ = (a6 + a5) * pb_;                                  \
                float n7_ = fmaf(sk[3], a5, a7 + a6) * p7_;                   \
                a0 = n0_; a1 = n1_; a2 = n2_; a3 = n3_;                       \
                a4 = n4_; a5 = n5_; a6 = n6_; a7 = n7_;                       \
            }                                                                 \
        }                                                                     \
    } while (0)

    // beta in hat space (s_hat = 510 - s): c = emit*b first, then same
    // upward stencil as forward; one cross-lane value (prev-lane c7).
#define COMPUTE_B(c8_, gb_, q1_, q3_, q5_, q7_) do {                          \
        _Pragma("unroll")                                                     \
        for (int r_ = 0; r_ < 8; ++r_) {                                      \
            int ti_ = (c8_) + r_;                                             \
            if (ti_ >= nsb) break;                                            \
            float pb_ = fast_exp2(gb_[r_] * RCP_LN2);                         \
            float p1_ = fast_exp2(q1_[r_] * RCP_LN2);                         \
            float p3_ = fast_exp2(q3_[r_] * RCP_LN2);                         \
            float p5_ = fast_exp2(q5_[r_] * RCP_LN2);                         \
            float p7_ = fast_exp2(q7_[r_] * RCP_LN2);                         \
            float c0_ = pb_ * a0, c1_ = p1_ * a1;                             \
            float c2_ = pb_ * a2, c3_ = p3_ * a3;                             \
            float c4_ = pb_ * a4, c5_ = p5_ * a5;                             \
            float c6_ = pb_ * a6, c7_ = p7_ * a7;                             \
            float P_ = dpp_shr1_f(c7_) * scale_d;                             \
            a0 = c0_ + P_;                                                    \
            a1 = fmaf(aH[0], P_,  c1_ + c0_);                                 \
            a2 = c2_ + c1_;                                                   \
            a3 = fmaf(aH[1], c1_, c3_ + c2_);                                 \
            a4 = c4_ + c3_;                                                   \
            a5 = fmaf(aH[2], c3_, c5_ + c4_);                                 \
            a6 = c6_ + c5_;                                                   \
            a7 = fmaf(aH[3], c5_, c7_ + c6_);                                 \
        }                                                                     \
    } while (0)

#define PHASE_F(k_, GB_, GS_, CS_, IB_, F_) do {                              \
        VMWAIT16();                                                           \
        GATHER(rowsF, GB_, labidx, gb##GS_, q1##GS_, q3##GS_, q5##GS_, q7##GS_); \
        COMPUTE_F((k_) * 8, F_, gb##CS_, q1##CS_, q3##CS_, q5##CS_, q7##CS_); \
        BOUNDARY();                                                           \
        ISSUE(rowsF, IB_, (k_) + 3, TMAP_F);                                  \
    } while (0)

#define PHASE_B(k_, GB_, GS_, CS_, IB_) do {                                  \
        VMWAIT16();                                                           \
        GATHER(rowsB, GB_, labH, gb##GS_, q1##GS_, q3##GS_, q5##GS_, q7##GS_); \
        COMPUTE_B((k_) * 8, gb##CS_, q1##CS_, q3##CS_, q5##CS_, q7##CS_);     \
        BOUNDARY();                                                           \
        ISSUE(rowsB, IB_, (k_) + 3, TMAP_B);                                  \
    } while (0)

    if (wid == 0) {
        // ===================== forward wave: alpha 0..mid-1 =====================
        int labidx[4];
        float sk[4];
#pragma unroll
        for (int jj = 0; jj < 4; ++jj) {
            int s = lane * 8 + 2 * jj + 1;
            int i = (s - 1) >> 1;
            int lab = 0;
            float al = 0.0f;
            if (i < S_DIM) {
                lab = tgt[i];
                if (s >= 3 && i >= 1) al = (tgt[i] != tgt[i - 1]) ? 1.0f : 0.0f;
            }
            if (lab < 0 || lab >= C_DIM) lab = 0;
            labidx[jj] = lab;
            sk[jj] = al;
        }

        float a0 = 0.0f, a1 = 0.0f, a2 = 0.0f, a3 = 0.0f;
        float a4 = 0.0f, a5 = 0.0f, a6 = 0.0f, a7 = 0.0f;
        int E = 0;
        float scale_d = (lane == 0) ? 0.0f : 1.0f;
        float gbA[8], q1A[8], q3A[8], q5A[8], q7A[8];
        float gbB[8], q1B[8], q3B[8], q5B[8], q7B[8];

        ISSUE(rowsF, 0, 0, TMAP_F);
        ISSUE(rowsF, 1, 1, TMAP_F);
        VMWAIT16();
        GATHER(rowsF, 0, labidx, gbA, q1A, q3A, q5A, q7A);
        ISSUE(rowsF, 2, 2, TMAP_F);

        const int ncf = (mid + 7) >> 3;
        const int kmaxf = ((ncf + 5) / 6) * 6;
        for (int k6 = 0; k6 < kmaxf; k6 += 6) {
            bool f0 = (k6 == 0);
            PHASE_F(k6 + 0, 1, B, A, 0, f0);
            PHASE_F(k6 + 1, 2, A, B, 1, false);
            PHASE_F(k6 + 2, 0, B, A, 2, false);
            PHASE_F(k6 + 3, 1, A, B, 0, false);
            PHASE_F(k6 + 4, 2, B, A, 1, false);
            PHASE_F(k6 + 5, 0, A, B, 2, false);
        }

        float4 lo = make_float4(a0, a1, a2, a3);
        float4 hi = make_float4(a4, a5, a6, a7);
        reinterpret_cast<float4*>(afin)[lane * 2] = lo;
        reinterpret_cast<float4*>(afin)[lane * 2 + 1] = hi;
        escF[lane] = E;
    } else {
        // ===================== backward wave: beta lenc-1..mid =====================
        // hat space: s_hat = 510 - s; even hat = blank (parity preserved)
        int labH[4];
        float aH[4];
#pragma unroll
        for (int jj = 0; jj < 4; ++jj) {
            int shat = lane * 8 + 2 * jj + 1;
            int s = 510 - shat;               // odd when shat odd
            int lab = 0;
            float al = 0.0f;
            if (s >= 1 && s <= 399) {
                lab = tgt[(s - 1) >> 1];
                if (s + 2 <= 400) al = (tgt[(s + 1) >> 1] != tgt[(s - 1) >> 1]) ? 1.0f : 0.0f;
            }
            if (lab < 0 || lab >= C_DIM) lab = 0;
            labH[jj] = lab;
            aH[jj] = al;
        }

        float a0, a1, a2, a3, a4, a5, a6, a7;
#define BINIT(aj_, j_) do {                                                   \
            int s_ = 510 - (lane * 8 + (j_));                                 \
            aj_ = (s_ == 2 * tl || (tl > 0 && s_ == 2 * tl - 1)) ? 1.0f : 0.0f; \
        } while (0)
        BINIT(a0, 0); BINIT(a1, 1); BINIT(a2, 2); BINIT(a3, 3);
        BINIT(a4, 4); BINIT(a5, 5); BINIT(a6, 6); BINIT(a7, 7);
#undef BINIT
        int E = 0;
        float scale_d = (lane == 0) ? 0.0f : 1.0f;
        float gbA[8], q1A[8], q3A[8], q5A[8], q7A[8];
        float gbB[8], q1B[8], q3B[8], q5B[8], q7B[8];

        ISSUE(rowsB, 0, 0, TMAP_B);
        ISSUE(rowsB, 1, 1, TMAP_B);
        VMWAIT16();
        GATHER(rowsB, 0, labH, gbA, q1A, q3A, q5A, q7A);
        ISSUE(rowsB, 2, 2, TMAP_B);

        const int ncb = (nsb + 7) >> 3;
        const int kmaxb = ((ncb + 5) / 6) * 6;
        for (int k6 = 0; k6 < kmaxb; k6 += 6) {
            PHASE_B(k6 + 0, 1, B, A, 0);
            PHASE_B(k6 + 1, 2, A, B, 1);
            PHASE_B(k6 + 2, 0, B, A, 2);
            PHASE_B(k6 + 3, 1, A, B, 0);
            PHASE_B(k6 + 4, 2, B, A, 1);
            PHASE_B(k6 + 5, 0, A, B, 2);
        }

        float4 lo = make_float4(a0, a1, a2, a3);
        float4 hi = make_float4(a4, a5, a6, a7);
        reinterpret_cast<float4*>(bfin)[lane * 2] = lo;
        reinterpret_cast<float4*>(bfin)[lane * 2 + 1] = hi;
        escB[lane] = E;
    }

    __syncthreads();

    if (tid < 64) {
        // total = sum_s alpha_{mid-1}[s] * beta_{mid-1}[s], in log2 domain
        const int l = lane;
        const int Ef = escF[l];
        float m8 = -1e30f, s8 = 0.0f;
#pragma unroll
        for (int j = 0; j < 8; ++j) {
            int s = 8 * l + j;
            float x = -1e30f;
            if (s <= 400) {
                float af = afin[s];
                int shat = 510 - s;
                float bf = bfin[shat];
                if (af > 0.0f && bf > 0.0f)
                    x = fast_log2(af) + fast_log2(bf) + (float)(Ef + escB[shat >> 3]);
            }
            float m2 = fmaxf(m8, x);
            s8 = s8 * fast_exp2(m8 - m2) + fast_exp2(x - m2);
            m8 = m2;
        }
        // wave-level LSE butterfly over 64 lanes
        float M = m8, V = s8;
#pragma unroll
        for (int off = 1; off < 64; off <<= 1) {
            float Mo = __shfl_xor(M, off);
            float Vo = __shfl_xor(V, off);
            float Mn = fmaxf(M, Mo);
            V = V * fast_exp2(M - Mn) + Vo * fast_exp2(Mo - Mn);
            M = Mn;
        }
        if (l == 0) {
            float X = M + fast_log2(V);
            float per_ex = -LN2F * X;
            if (!(per_ex < 1e29f)) per_ex = 0.0f;  // zero_infinity (NaN/inf safe)
            float tlf = (float)tl;
            if (tlf < 1.0f) tlf = 1.0f;
            ws_loss[n] = per_ex / sqrtf(tlf);
        }
    }
#undef ISSUE
#undef GATHER
#undef BOUNDARY
#undef COMPUTE_F
#undef COMPUTE_B
#undef PHASE_F
#undef PHASE_B
#undef TMAP_F
#undef TMAP_B
}

__global__ __launch_bounds__(64) void ctc_reduce(const float* __restrict__ wsf,
                                                 float* __restrict__ out)
{
    int l = threadIdx.x;
    float v = (l < N_DIM) ? wsf[l] : 0.0f;
#pragma unroll
    for (int off = 32; off >= 1; off >>= 1) v += __shfl_down(v, off);
    if (l == 0) out[0] = v * (1.0f / N_DIM);
}

extern "C" void kernel_launch(void* const* d_in, const int* in_sizes, int n_in,
                              void* d_out, int out_size, void* d_ws, size_t ws_size,
                              hipStream_t stream) {
    (void)in_sizes; (void)n_in; (void)out_size; (void)ws_size;
    const float* lp   = (const float*)d_in[0];
    const int* tgts   = (const int*)d_in[1];
    const int* ilens  = (const int*)d_in[2];
    const int* tlens  = (const int*)d_in[3];
    float* wsf = (float*)d_ws;

    ctc_dp<<<N_DIM, 128, 0, stream>>>(lp, tgts, ilens, tlens, wsf);
    ctc_reduce<<<1, 64, 0, stream>>>(wsf, (float*)d_out);
}

// Round 8
// 292.339 us; speedup vs baseline: 2.2597x; 1.0071x over previous
//
#include <hip/hip_runtime.h>
#include <hip/hip_bf16.h>

#define T_DIM 1600
#define N_DIM 32
#define C_DIM 512
#define S_DIM 200
#define L_DIM 401
#define RCP_LN2 1.44269504088896340736f
#define LN2F 0.69314718055994530942f
#define ESENT (-(1 << 28))

static __device__ __forceinline__ float fast_exp2(float x) {
#if __has_builtin(__builtin_amdgcn_exp2f)
    return __builtin_amdgcn_exp2f(x);
#else
    return exp2f(x);
#endif
}

static __device__ __forceinline__ float fast_log2(float x) {
#if __has_builtin(__builtin_amdgcn_logf)
    return __builtin_amdgcn_logf(x);
#else
    return log2f(x);
#endif
}

// ---- DPP cross-lane helpers (VALU pipe) ----
static __device__ __forceinline__ float dpp_shr1_f(float x) {
    return __int_as_float(__builtin_amdgcn_update_dpp(
        0, __float_as_int(x), 0x138, 0xf, 0xf, false));  // lane0 -> 0.0f
}
static __device__ __forceinline__ int dpp_shr1_i(int x, int old0) {
    return __builtin_amdgcn_update_dpp(old0, x, 0x138, 0xf, 0xf, false);
}
static __device__ __forceinline__ int dpp_prefix_max_i(int x) {
    int t;
    t = __builtin_amdgcn_update_dpp(x, x, 0x111, 0xf, 0xf, false); x = (t > x) ? t : x;
    t = __builtin_amdgcn_update_dpp(x, x, 0x112, 0xf, 0xf, false); x = (t > x) ? t : x;
    t = __builtin_amdgcn_update_dpp(x, x, 0x114, 0xf, 0xf, false); x = (t > x) ? t : x;
    t = __builtin_amdgcn_update_dpp(x, x, 0x118, 0xf, 0xf, false); x = (t > x) ? t : x;
    t = __builtin_amdgcn_update_dpp(x, x, 0x142, 0xf, 0xf, false); x = (t > x) ? t : x;
    t = __builtin_amdgcn_update_dpp(x, x, 0x143, 0xf, 0xf, false); x = (t > x) ? t : x;
    return x;
}

// async HBM -> LDS, 16 B/lane; lds base wave-uniform (HW adds lane*16)
static __device__ __forceinline__ void gl_lds16(const float* g, float* l) {
    __builtin_amdgcn_global_load_lds(
        (const __attribute__((address_space(1))) unsigned int*)g,
        (__attribute__((address_space(3))) unsigned int*)l, 16, 0, 0);
}

#define VMWAIT16() __builtin_amdgcn_s_waitcnt(0x4F70)  // vmcnt(16)

__global__ __launch_bounds__(128) void ctc_dp(
    const float* __restrict__ lp, const int* __restrict__ tgts,
    const int* __restrict__ input_lens, const int* __restrict__ target_lens,
    float* __restrict__ out)
{
    __shared__ float rowsF[3][8][C_DIM];   // 48 KB fwd staging
    __shared__ float rowsB[3][8][C_DIM];   // 48 KB bwd staging
    __shared__ float afin[512];
    __shared__ float bfin[512];            // hat-indexed beta
    __shared__ int escF[64];
    __shared__ int escB[64];

    const int n = blockIdx.x;
    const int tid = threadIdx.x;
    const int wid = tid >> 6;
    const int lane = tid & 63;
    const int* tgt = tgts + n * S_DIM;

    int len = input_lens[n];
    if (len > T_DIM) len = T_DIM;
    const int lenc = (len < 1) ? 1 : len;
    const int tl = target_lens[n];
    const int mid = (lenc + 1) >> 1;   // forward steps t=0..mid-1
    const int nsb = lenc - mid;        // backward steps t=lenc-1..mid

#define TMAP_F(ti_) ((ti_) > mid - 1 ? mid - 1 : (ti_))
#define TMAP_B(ti_) (lenc - 1 - (ti_) < 0 ? 0 : lenc - 1 - (ti_))

#define ISSUE(RW_, B_, c_, TMAP_) do {                                        \
        int tb_ = (c_) * 8;                                                   \
        _Pragma("unroll")                                                     \
        for (int r_ = 0; r_ < 8; ++r_) {                                      \
            int ti_ = tb_ + r_;                                               \
            int t_ = TMAP_(ti_);                                              \
            const float* g_ = lp + ((size_t)t_ * N_DIM + n) * C_DIM + lane*4; \
            gl_lds16(g_,       &RW_[(B_)][r_][0]);                            \
            gl_lds16(g_ + 256, &RW_[(B_)][r_][256]);                          \
        }                                                                     \
    } while (0)

    // Gather AND convert to linear probs (exp2 batched here, a full phase
    // before COMPUTE consumes them -> transcendental latency off-chain).
#define GATHER_CONV(RW_, B_, LAB_, pb_, p1_, p3_, p5_, p7_) do {              \
        _Pragma("unroll")                                                     \
        for (int r_ = 0; r_ < 8; ++r_) {                                      \
            pb_[r_] = fast_exp2(RW_[(B_)][r_][0]       * RCP_LN2);            \
            p1_[r_] = fast_exp2(RW_[(B_)][r_][LAB_[0]] * RCP_LN2);            \
            p3_[r_] = fast_exp2(RW_[(B_)][r_][LAB_[1]] * RCP_LN2);            \
            p5_[r_] = fast_exp2(RW_[(B_)][r_][LAB_[2]] * RCP_LN2);            \
            p7_[r_] = fast_exp2(RW_[(B_)][r_][LAB_[3]] * RCP_LN2);            \
        }                                                                     \
    } while (0)

#define BOUNDARY() do {                                                       \
        float lm_ = fmaxf(fmaxf(fmaxf(a0, a1), fmaxf(a2, a3)),                \
                          fmaxf(fmaxf(a4, a5), fmaxf(a6, a7)));               \
        bool nz_ = (lm_ > 0.0f);                                              \
        int kl_ = (int)((__float_as_uint(lm_) >> 23) & 0xffu) - 127;          \
        int prop_ = nz_ ? (E + kl_) : ESENT;                                  \
        int g_ = dpp_prefix_max_i(prop_ + 32 * lane);                         \
        int Efin_ = g_ - 32 * lane;                                           \
        if (nz_) {                                                            \
            int sh_ = E - Efin_;                                              \
            int h1_ = sh_ / 2, h2_ = sh_ - h1_;                               \
            float f_ = fast_exp2((float)h1_), gg_ = fast_exp2((float)h2_);    \
            float fg_ = f_ * gg_;                                             \
            a0 *= fg_; a1 *= fg_; a2 *= fg_; a3 *= fg_;                       \
            a4 *= fg_; a5 *= fg_; a6 *= fg_; a7 *= fg_;                       \
        }                                                                     \
        int Eprev_ = dpp_shr1_i(Efin_, ESENT);                                \
        E = Efin_;                                                            \
        if (lane == 0) {                                                      \
            scale_d = 0.0f;                                                   \
        } else {                                                              \
            int d_ = Eprev_ - Efin_;      /* <= 32 by construction */         \
            scale_d = (d_ < -126) ? 0.0f : fast_exp2((float)d_);              \
        }                                                                     \
    } while (0)

    // pure fma/mul DP steps from pre-converted probs (no transcendentals)
#define COMPUTE_F(c8_, FIRST_, pb_, p1_, p3_, p5_, p7_) do {                  \
        _Pragma("unroll")                                                     \
        for (int r_ = 0; r_ < 8; ++r_) {                                      \
            int t_ = (c8_) + r_;                                              \
            if (t_ >= mid) break;                                             \
            if ((FIRST_) && r_ == 0) {                                        \
                if (lane == 0) {                                              \
                    a0 = pb_[0];                                              \
                    a1 = (tl >= 1) ? p1_[0] : 0.0f;                           \
                }                                                             \
            } else {                                                          \
                float P_ = dpp_shr1_f(a7) * scale_d;                          \
                float n0_ = (a0 + P_) * pb_[r_];                              \
                float n1_ = fmaf(sk[0], P_,  a1 + a0) * p1_[r_];              \
                float n2_ = (a2 + a1) * pb_[r_];                              \
                float n3_ = fmaf(sk[1], a1, a3 + a2) * p3_[r_];               \
                float n4_ = (a4 + a3) * pb_[r_];                              \
                float n5_ = fmaf(sk[2], a3, a5 + a4) * p5_[r_];               \
                float n6_ = (a6 + a5) * pb_[r_];                              \
                float n7_ = fmaf(sk[3], a5, a7 + a6) * p7_[r_];               \
                a0 = n0_; a1 = n1_; a2 = n2_; a3 = n3_;                       \
                a4 = n4_; a5 = n5_; a6 = n6_; a7 = n7_;                       \
            }                                                                 \
        }                                                                     \
    } while (0)

#define COMPUTE_B(c8_, pb_, p1_, p3_, p5_, p7_) do {                          \
        _Pragma("unroll")                                                     \
        for (int r_ = 0; r_ < 8; ++r_) {                                      \
            int ti_ = (c8_) + r_;                                             \
            if (ti_ >= nsb) break;                                            \
            float c0_ = pb_[r_] * a0, c1_ = p1_[r_] * a1;                     \
            float c2_ = pb_[r_] * a2, c3_ = p3_[r_] * a3;                     \
            float c4_ = pb_[r_] * a4, c5_ = p5_[r_] * a5;                     \
            float c6_ = pb_[r_] * a6, c7_ = p7_[r_] * a7;                     \
            float P_ = dpp_shr1_f(c7_) * scale_d;                             \
            a0 = c0_ + P_;                                                    \
            a1 = fmaf(aH[0], P_,  c1_ + c0_);                                 \
            a2 = c2_ + c1_;                                                   \
            a3 = fmaf(aH[1], c1_, c3_ + c2_);                                 \
            a4 = c4_ + c3_;                                                   \
            a5 = fmaf(aH[2], c3_, c5_ + c4_);                                 \
            a6 = c6_ + c5_;                                                   \
            a7 = fmaf(aH[3], c5_, c7_ + c6_);                                 \
        }                                                                     \
    } while (0)

#define PHASE_F(k_, GB_, GS_, CS_, IB_, F_) do {                              \
        VMWAIT16();                                                           \
        GATHER_CONV(rowsF, GB_, labidx,                                       \
                    pb##GS_, p1##GS_, p3##GS_, p5##GS_, p7##GS_);             \
        COMPUTE_F((k_) * 8, F_, pb##CS_, p1##CS_, p3##CS_, p5##CS_, p7##CS_); \
        BOUNDARY();                                                           \
        ISSUE(rowsF, IB_, (k_) + 3, TMAP_F);                                  \
    } while (0)

#define PHASE_B(k_, GB_, GS_, CS_, IB_) do {                                  \
        VMWAIT16();                                                           \
        GATHER_CONV(rowsB, GB_, labH,                                         \
                    pb##GS_, p1##GS_, p3##GS_, p5##GS_, p7##GS_);             \
        COMPUTE_B((k_) * 8, pb##CS_, p1##CS_, p3##CS_, p5##CS_, p7##CS_);     \
        BOUNDARY();                                                           \
        ISSUE(rowsB, IB_, (k_) + 3, TMAP_B);                                  \
    } while (0)

    if (wid == 0) {
        // =============== forward wave: alpha 0..mid-1 ===============
        int labidx[4];
        float sk[4];
#pragma unroll
        for (int jj = 0; jj < 4; ++jj) {
            int s = lane * 8 + 2 * jj + 1;
            int i = (s - 1) >> 1;
            int lab = 0;
            float al = 0.0f;
            if (i < S_DIM) {
                lab = tgt[i];
                if (s >= 3 && i >= 1) al = (tgt[i] != tgt[i - 1]) ? 1.0f : 0.0f;
            }
            if (lab < 0 || lab >= C_DIM) lab = 0;
            labidx[jj] = lab;
            sk[jj] = al;
        }

        float a0 = 0.0f, a1 = 0.0f, a2 = 0.0f, a3 = 0.0f;
        float a4 = 0.0f, a5 = 0.0f, a6 = 0.0f, a7 = 0.0f;
        int E = 0;
        float scale_d = (lane == 0) ? 0.0f : 1.0f;
        float pbA[8], p1A[8], p3A[8], p5A[8], p7A[8];
        float pbB[8], p1B[8], p3B[8], p5B[8], p7B[8];

        ISSUE(rowsF, 0, 0, TMAP_F);
        ISSUE(rowsF, 1, 1, TMAP_F);
        VMWAIT16();
        GATHER_CONV(rowsF, 0, labidx, pbA, p1A, p3A, p5A, p7A);
        ISSUE(rowsF, 2, 2, TMAP_F);

        const int ncf = (mid + 7) >> 3;
        const int kmaxf = ((ncf + 5) / 6) * 6;
        for (int k6 = 0; k6 < kmaxf; k6 += 6) {
            bool f0 = (k6 == 0);
            PHASE_F(k6 + 0, 1, B, A, 0, f0);
            PHASE_F(k6 + 1, 2, A, B, 1, false);
            PHASE_F(k6 + 2, 0, B, A, 2, false);
            PHASE_F(k6 + 3, 1, A, B, 0, false);
            PHASE_F(k6 + 4, 2, B, A, 1, false);
            PHASE_F(k6 + 5, 0, A, B, 2, false);
        }

        float4 lo = make_float4(a0, a1, a2, a3);
        float4 hi = make_float4(a4, a5, a6, a7);
        reinterpret_cast<float4*>(afin)[lane * 2] = lo;
        reinterpret_cast<float4*>(afin)[lane * 2 + 1] = hi;
        escF[lane] = E;
    } else {
        // =============== backward wave: beta lenc-1..mid ===============
        // hat space: s_hat = 510 - s; even hat = blank (parity preserved)
        int labH[4];
        float aH[4];
#pragma unroll
        for (int jj = 0; jj < 4; ++jj) {
            int shat = lane * 8 + 2 * jj + 1;
            int s = 510 - shat;
            int lab = 0;
            float al = 0.0f;
            if (s >= 1 && s <= 399) {
                lab = tgt[(s - 1) >> 1];
                if (s + 2 <= 400) al = (tgt[(s + 1) >> 1] != tgt[(s - 1) >> 1]) ? 1.0f : 0.0f;
            }
            if (lab < 0 || lab >= C_DIM) lab = 0;
            labH[jj] = lab;
            aH[jj] = al;
        }

        float a0, a1, a2, a3, a4, a5, a6, a7;
#define BINIT(aj_, j_) do {                                                   \
            int s_ = 510 - (lane * 8 + (j_));                                 \
            aj_ = (s_ == 2 * tl || (tl > 0 && s_ == 2 * tl - 1)) ? 1.0f : 0.0f; \
        } while (0)
        BINIT(a0, 0); BINIT(a1, 1); BINIT(a2, 2); BINIT(a3, 3);
        BINIT(a4, 4); BINIT(a5, 5); BINIT(a6, 6); BINIT(a7, 7);
#undef BINIT
        int E = 0;
        float scale_d = (lane == 0) ? 0.0f : 1.0f;
        float pbA[8], p1A[8], p3A[8], p5A[8], p7A[8];
        float pbB[8], p1B[8], p3B[8], p5B[8], p7B[8];

        ISSUE(rowsB, 0, 0, TMAP_B);
        ISSUE(rowsB, 1, 1, TMAP_B);
        VMWAIT16();
        GATHER_CONV(rowsB, 0, labH, pbA, p1A, p3A, p5A, p7A);
        ISSUE(rowsB, 2, 2, TMAP_B);

        const int ncb = (nsb + 7) >> 3;
        const int kmaxb = ((ncb + 5) / 6) * 6;
        for (int k6 = 0; k6 < kmaxb; k6 += 6) {
            PHASE_B(k6 + 0, 1, B, A, 0);
            PHASE_B(k6 + 1, 2, A, B, 1);
            PHASE_B(k6 + 2, 0, B, A, 2);
            PHASE_B(k6 + 3, 1, A, B, 0);
            PHASE_B(k6 + 4, 2, B, A, 1);
            PHASE_B(k6 + 5, 0, A, B, 2);
        }

        float4 lo = make_float4(a0, a1, a2, a3);
        float4 hi = make_float4(a4, a5, a6, a7);
        reinterpret_cast<float4*>(bfin)[lane * 2] = lo;
        reinterpret_cast<float4*>(bfin)[lane * 2 + 1] = hi;
        escB[lane] = E;
    }

    __syncthreads();

    if (tid < 64) {
        // total = sum_s alpha_{mid-1}[s] * beta_{mid-1}[s], log2 domain
        const int l = lane;
        const int Ef = escF[l];
        float m8 = -1e30f, s8 = 0.0f;
#pragma unroll
        for (int j = 0; j < 8; ++j) {
            int s = 8 * l + j;
            float x = -1e30f;
            if (s <= 400) {
                float af = afin[s];
                int shat = 510 - s;
                float bf = bfin[shat];
                if (af > 0.0f && bf > 0.0f)
                    x = fast_log2(af) + fast_log2(bf) + (float)(Ef + escB[shat >> 3]);
            }
            float m2 = fmaxf(m8, x);
            s8 = s8 * fast_exp2(m8 - m2) + fast_exp2(x - m2);
            m8 = m2;
        }
        float M = m8, V = s8;
#pragma unroll
        for (int off = 1; off < 64; off <<= 1) {
            float Mo = __shfl_xor(M, off);
            float Vo = __shfl_xor(V, off);
            float Mn = fmaxf(M, Mo);
            V = V * fast_exp2(M - Mn) + Vo * fast_exp2(Mo - Mn);
            M = Mn;
        }
        if (l == 0) {
            float X = M + fast_log2(V);
            float per_ex = -LN2F * X;
            if (!(per_ex < 1e29f)) per_ex = 0.0f;  // zero_infinity (NaN/inf safe)
            float tlf = (float)tl;
            if (tlf < 1.0f) tlf = 1.0f;
            // fused mean: one device-scope atomic per block (32 total)
            atomicAdd(out, per_ex / sqrtf(tlf) * (1.0f / N_DIM));
        }
    }
#undef ISSUE
#undef GATHER_CONV
#undef BOUNDARY
#undef COMPUTE_F
#undef COMPUTE_B
#undef PHASE_F
#undef PHASE_B
#undef TMAP_F
#undef TMAP_B
}

extern "C" void kernel_launch(void* const* d_in, const int* in_sizes, int n_in,
                              void* d_out, int out_size, void* d_ws, size_t ws_size,
                              hipStream_t stream) {
    (void)in_sizes; (void)n_in; (void)d_ws; (void)ws_size;
    const float* lp   = (const float*)d_in[0];
    const int* tgts   = (const int*)d_in[1];
    const int* ilens  = (const int*)d_in[2];
    const int* tlens  = (const int*)d_in[3];

    // d_out is poisoned (0xAA) before every timed launch -> zero it first.
    hipMemsetAsync(d_out, 0, (size_t)out_size * sizeof(float), stream);
    ctc_dp<<<N_DIM, 128, 0, stream>>>(lp, tgts, ilens, tlens, (float*)d_out);
}